// Round 4
// baseline (248.502 us; speedup 1.0000x reference)
//
#include <hip/hip_runtime.h>

#define C_COLS 16
#define NT 256
#define NB1 1024   // reduce grid — DO NOT change: partials row count defines the summation tree (absmax 0.0)
#define NB2 1024   // fill grid: 4 blocks/CU; halves redundant phase-A L2 traffic vs 2048

typedef float floatx4 __attribute__((ext_vector_type(4)));  // native vec for nontemporal builtin

// ---------------------------------------------------------------------------
// Kernel 1: grid-stride NaN-masked reduce -> per-block partials.
// 8-deep manual load batching (all loads issued before accumulation) for
// memory-level parallelism; accumulation order per thread is IDENTICAL to
// the original single-load loop (increasing i) -> bit-identical sums.
// ---------------------------------------------------------------------------
__global__ __launch_bounds__(NT) void k_reduce(const float4* __restrict__ x4,
                                               long long n4,
                                               float* __restrict__ partials) {
    const int tid = threadIdx.x;
    const long long gid = (long long)blockIdx.x * NT + tid;
    const long long stride = (long long)gridDim.x * NT;  // % 4 == 0

    float s0 = 0.f, s1 = 0.f, s2 = 0.f, s3 = 0.f;
    float c0 = 0.f, c1 = 0.f, c2 = 0.f, c3 = 0.f;

#define ACC(v)                                                              \
    do {                                                                    \
        bool m0 = ((v).x == (v).x); s0 += m0 ? (v).x : 0.f; c0 += m0 ? 1.f : 0.f; \
        bool m1 = ((v).y == (v).y); s1 += m1 ? (v).y : 0.f; c1 += m1 ? 1.f : 0.f; \
        bool m2 = ((v).z == (v).z); s2 += m2 ? (v).z : 0.f; c2 += m2 ? 1.f : 0.f; \
        bool m3 = ((v).w == (v).w); s3 += m3 ? (v).w : 0.f; c3 += m3 ? 1.f : 0.f; \
    } while (0)

    long long i = gid;
    for (; i + 7 * stride < n4; i += 8 * stride) {
        float4 va = x4[i];
        float4 vb = x4[i + stride];
        float4 vc = x4[i + 2 * stride];
        float4 vd = x4[i + 3 * stride];
        float4 ve = x4[i + 4 * stride];
        float4 vf = x4[i + 5 * stride];
        float4 vg = x4[i + 6 * stride];
        float4 vh = x4[i + 7 * stride];
        ACC(va); ACC(vb); ACC(vc); ACC(vd);
        ACC(ve); ACC(vf); ACC(vg); ACC(vh);
    }
    for (; i < n4; i += stride) {
        float4 v = x4[i];
        ACC(v);
    }
#undef ACC

    // Butterfly over lanes with identical (lane & 3): xor offsets 4,8,16,32.
    for (int off = 4; off < 64; off <<= 1) {
        s0 += __shfl_xor(s0, off, 64);
        s1 += __shfl_xor(s1, off, 64);
        s2 += __shfl_xor(s2, off, 64);
        s3 += __shfl_xor(s3, off, 64);
        c0 += __shfl_xor(c0, off, 64);
        c1 += __shfl_xor(c1, off, 64);
        c2 += __shfl_xor(c2, off, 64);
        c3 += __shfl_xor(c3, off, 64);
    }

    __shared__ float bsum[C_COLS];
    __shared__ float bcnt[C_COLS];
    if (tid < C_COLS) { bsum[tid] = 0.f; bcnt[tid] = 0.f; }
    __syncthreads();

    if ((tid & 63) < 4) {  // lanes 0..3 of each wave hold group totals
        const int cb4 = (tid & 3) * 4;
        atomicAdd(&bsum[cb4 + 0], s0);
        atomicAdd(&bsum[cb4 + 1], s1);
        atomicAdd(&bsum[cb4 + 2], s2);
        atomicAdd(&bsum[cb4 + 3], s3);
        atomicAdd(&bcnt[cb4 + 0], c0);
        atomicAdd(&bcnt[cb4 + 1], c1);
        atomicAdd(&bcnt[cb4 + 2], c2);
        atomicAdd(&bcnt[cb4 + 3], c3);
    }
    __syncthreads();

    if (tid < C_COLS) {
        partials[(long long)blockIdx.x * 32 + tid] = bsum[tid];
        partials[(long long)blockIdx.x * 32 + C_COLS + tid] = bcnt[tid];
    }
}

// ---------------------------------------------------------------------------
// Kernel 2: fill. Phase A: per-block redundant final reduce (identical tree
// to the original single-block k_final -> bit-identical mean; ~128 KB
// L2-broadcast per block, NB2=1024 keeps aggregate redundancy at ~134 MB).
// Phase B: 4-deep batched L3-hit loads (x stays L3-resident from K1) +
// nontemporal stores so the 128 MB write stream doesn't evict x from L3
// (proven in round 2: re-read was 100% L3-served).
// ---------------------------------------------------------------------------
__global__ __launch_bounds__(NT) void k_fill(const float4* __restrict__ x4,
                                             float4* __restrict__ o4,
                                             long long n4, long long n,
                                             const float* __restrict__ partials,
                                             int nb1) {
    const int tid = threadIdx.x;
    const long long gid = (long long)blockIdx.x * NT + tid;
    const long long stride = (long long)gridDim.x * NT;  // % 4 == 0

    // ---- phase A: per-block final reduce (same tree as original k_final) ----
    __shared__ float ssum[NT];
    __shared__ float scnt[NT];
    __shared__ float smean[C_COLS];
    {
        const int c = tid & 15;
        const int r0 = tid >> 4;  // 0..15
        float S = 0.f, Cn = 0.f;
        #pragma unroll 8
        for (int p = r0; p < nb1; p += 16) {
            S  += partials[(long long)p * 32 + c];
            Cn += partials[(long long)p * 32 + 16 + c];
        }
        ssum[tid] = S;
        scnt[tid] = Cn;
        __syncthreads();
        if (tid < 16) {
            float SS = 0.f, CC = 0.f;
            for (int r = 0; r < 16; ++r) {
                SS += ssum[r * 16 + tid];
                CC += scnt[r * 16 + tid];
            }
            // scalar tail (elements n4*4 .. n-1) — unused for this shape
            const float* x = (const float*)x4;
            for (long long j = n4 * 4; j < n; ++j) {
                if ((int)(j % 16) == tid) {
                    float v = x[j];
                    if (v == v) { SS += v; CC += 1.f; }
                }
            }
            smean[tid] = SS / fmaxf(CC, 1.f);
        }
        __syncthreads();
    }

    // ---- phase B: fill (4-deep batched loads, nt stores) ----
    const int cb = (int)(gid & 3) * 4;  // constant per thread (stride % 4 == 0)
    const float m0 = smean[cb + 0];
    const float m1 = smean[cb + 1];
    const float m2 = smean[cb + 2];
    const float m3 = smean[cb + 3];

#define FIX_ST(v, idx)                                                      \
    do {                                                                    \
        floatx4 nv;                                                         \
        nv.x = ((v).x == (v).x) ? (v).x : m0;                               \
        nv.y = ((v).y == (v).y) ? (v).y : m1;                               \
        nv.z = ((v).z == (v).z) ? (v).z : m2;                               \
        nv.w = ((v).w == (v).w) ? (v).w : m3;                               \
        __builtin_nontemporal_store(nv, (floatx4*)&o4[idx]);                \
    } while (0)

    long long i = gid;
    for (; i + 3 * stride < n4; i += 4 * stride) {
        float4 va = x4[i];
        float4 vb = x4[i + stride];
        float4 vc = x4[i + 2 * stride];
        float4 vd = x4[i + 3 * stride];
        FIX_ST(va, i);
        FIX_ST(vb, i + stride);
        FIX_ST(vc, i + 2 * stride);
        FIX_ST(vd, i + 3 * stride);
    }
    for (; i < n4; i += stride) {
        float4 v = x4[i];
        FIX_ST(v, i);
    }
#undef FIX_ST

    if (gid == 0) {  // scalar tail (unused for this shape)
        const float* x = (const float*)x4;
        float* o = (float*)o4;
        for (long long j = n4 * 4; j < n; ++j) {
            float v = x[j];
            o[j] = (v == v) ? v : smean[(int)(j % 16)];
        }
    }
}

extern "C" void kernel_launch(void* const* d_in, const int* in_sizes, int n_in,
                              void* d_out, int out_size, void* d_ws, size_t ws_size,
                              hipStream_t stream) {
    const float* x = (const float*)d_in[0];
    float* out = (float*)d_out;
    const long long n = (long long)in_sizes[0];
    const long long n4 = n / 4;

    // ws layout: [nb1 * 32] partial sums/counts.
    int nb1 = NB1;
    {
        long long cap = (long long)(ws_size / 4) / 32;
        if (cap < 1) cap = 1;
        if (nb1 > cap) nb1 = (int)cap;
    }
    float* partials = (float*)d_ws;

    k_reduce<<<nb1, NT, 0, stream>>>((const float4*)x, n4, partials);
    k_fill<<<NB2, NT, 0, stream>>>((const float4*)x, (float4*)out, n4, n,
                                   partials, nb1);
}

// Round 6
// 245.626 us; speedup vs baseline: 1.0117x; 1.0117x over previous
//
#include <hip/hip_runtime.h>

#define C_COLS 16
#define NT 256
#define NB1 1024   // reduce grid — DO NOT change: partials row count defines the summation tree (absmax 0.0)
#define NB2 2048   // fill grid: 8 blocks/CU -> full 32 waves/CU for the write stream

// ---------------------------------------------------------------------------
// Kernel 1: grid-stride NaN-masked reduce -> per-block partials.
// 8-deep manual load batching; tail also issues its loads batched
// (predicated). Accumulation (ACC) order is increasing i in all paths ->
// per-thread sums bit-identical to the original single-load loop.
// ---------------------------------------------------------------------------
__global__ __launch_bounds__(NT) void k_reduce(const float4* __restrict__ x4,
                                               long long n4,
                                               float* __restrict__ partials) {
    const int tid = threadIdx.x;
    const long long gid = (long long)blockIdx.x * NT + tid;
    const long long stride = (long long)gridDim.x * NT;  // % 4 == 0

    float s0 = 0.f, s1 = 0.f, s2 = 0.f, s3 = 0.f;
    float c0 = 0.f, c1 = 0.f, c2 = 0.f, c3 = 0.f;

#define ACC(v)                                                              \
    do {                                                                    \
        bool m0 = ((v).x == (v).x); s0 += m0 ? (v).x : 0.f; c0 += m0 ? 1.f : 0.f; \
        bool m1 = ((v).y == (v).y); s1 += m1 ? (v).y : 0.f; c1 += m1 ? 1.f : 0.f; \
        bool m2 = ((v).z == (v).z); s2 += m2 ? (v).z : 0.f; c2 += m2 ? 1.f : 0.f; \
        bool m3 = ((v).w == (v).w); s3 += m3 ? (v).w : 0.f; c3 += m3 ? 1.f : 0.f; \
    } while (0)

    long long i = gid;
    for (; i + 7 * stride < n4; i += 8 * stride) {
        float4 va = x4[i];
        float4 vb = x4[i + stride];
        float4 vc = x4[i + 2 * stride];
        float4 vd = x4[i + 3 * stride];
        float4 ve = x4[i + 4 * stride];
        float4 vf = x4[i + 5 * stride];
        float4 vg = x4[i + 6 * stride];
        float4 vh = x4[i + 7 * stride];
        ACC(va); ACC(vb); ACC(vc); ACC(vd);
        ACC(ve); ACC(vf); ACC(vg); ACC(vh);
    }
    // Batched predicated tail (<=7 iters): loads issued together, ACC in
    // increasing-i order -> identical summation order to a serial tail.
    {
        float4 t0, t1, t2, t3, t4, t5, t6;
        bool h0 = (i + 0 * stride) < n4;
        bool h1 = (i + 1 * stride) < n4;
        bool h2 = (i + 2 * stride) < n4;
        bool h3 = (i + 3 * stride) < n4;
        bool h4 = (i + 4 * stride) < n4;
        bool h5 = (i + 5 * stride) < n4;
        bool h6 = (i + 6 * stride) < n4;
        if (h0) t0 = x4[i + 0 * stride];
        if (h1) t1 = x4[i + 1 * stride];
        if (h2) t2 = x4[i + 2 * stride];
        if (h3) t3 = x4[i + 3 * stride];
        if (h4) t4 = x4[i + 4 * stride];
        if (h5) t5 = x4[i + 5 * stride];
        if (h6) t6 = x4[i + 6 * stride];
        if (h0) ACC(t0);
        if (h1) ACC(t1);
        if (h2) ACC(t2);
        if (h3) ACC(t3);
        if (h4) ACC(t4);
        if (h5) ACC(t5);
        if (h6) ACC(t6);
    }
#undef ACC

    // Butterfly over lanes with identical (lane & 3): xor offsets 4,8,16,32.
    for (int off = 4; off < 64; off <<= 1) {
        s0 += __shfl_xor(s0, off, 64);
        s1 += __shfl_xor(s1, off, 64);
        s2 += __shfl_xor(s2, off, 64);
        s3 += __shfl_xor(s3, off, 64);
        c0 += __shfl_xor(c0, off, 64);
        c1 += __shfl_xor(c1, off, 64);
        c2 += __shfl_xor(c2, off, 64);
        c3 += __shfl_xor(c3, off, 64);
    }

    __shared__ float bsum[C_COLS];
    __shared__ float bcnt[C_COLS];
    if (tid < C_COLS) { bsum[tid] = 0.f; bcnt[tid] = 0.f; }
    __syncthreads();

    if ((tid & 63) < 4) {  // lanes 0..3 of each wave hold group totals
        const int cb4 = (tid & 3) * 4;
        atomicAdd(&bsum[cb4 + 0], s0);
        atomicAdd(&bsum[cb4 + 1], s1);
        atomicAdd(&bsum[cb4 + 2], s2);
        atomicAdd(&bsum[cb4 + 3], s3);
        atomicAdd(&bcnt[cb4 + 0], c0);
        atomicAdd(&bcnt[cb4 + 1], c1);
        atomicAdd(&bcnt[cb4 + 2], c2);
        atomicAdd(&bcnt[cb4 + 3], c3);
    }
    __syncthreads();

    if (tid < C_COLS) {
        partials[(long long)blockIdx.x * 32 + tid] = bsum[tid];
        partials[(long long)blockIdx.x * 32 + C_COLS + tid] = bcnt[tid];
    }
}

// ---------------------------------------------------------------------------
// Kernel 2: fill. First-4-tile loads are issued BEFORE phase A so their L3
// latency hides under the partials reduce. Phase A: per-block redundant
// final reduce (identical tree to the original single-block k_final ->
// bit-identical mean). Phase B: NORMAL stores (A/B vs nontemporal: the
// rocclr fill proves normal stores reach 6.7 TB/s; testing whether nt
// stores were throttling the write stream).
// ---------------------------------------------------------------------------
__global__ __launch_bounds__(NT) void k_fill(const float4* __restrict__ x4,
                                             float4* __restrict__ o4,
                                             long long n4, long long n,
                                             const float* __restrict__ partials,
                                             int nb1) {
    const int tid = threadIdx.x;
    const long long gid = (long long)blockIdx.x * NT + tid;
    const long long stride = (long long)gridDim.x * NT;  // % 4 == 0

    // ---- prefetch first 4 tiles (overlaps phase A latency) ----
    float4 pa, pb, pc, pd;
    const bool ha = (gid + 0 * stride) < n4;
    const bool hb = (gid + 1 * stride) < n4;
    const bool hc = (gid + 2 * stride) < n4;
    const bool hd = (gid + 3 * stride) < n4;
    if (ha) pa = x4[gid + 0 * stride];
    if (hb) pb = x4[gid + 1 * stride];
    if (hc) pc = x4[gid + 2 * stride];
    if (hd) pd = x4[gid + 3 * stride];

    // ---- phase A: per-block final reduce (same tree as original k_final) ----
    __shared__ float ssum[NT];
    __shared__ float scnt[NT];
    __shared__ float smean[C_COLS];
    {
        const int c = tid & 15;
        const int r0 = tid >> 4;  // 0..15
        float S = 0.f, Cn = 0.f;
        #pragma unroll 8
        for (int p = r0; p < nb1; p += 16) {
            S  += partials[(long long)p * 32 + c];
            Cn += partials[(long long)p * 32 + 16 + c];
        }
        ssum[tid] = S;
        scnt[tid] = Cn;
        __syncthreads();
        if (tid < 16) {
            float SS = 0.f, CC = 0.f;
            for (int r = 0; r < 16; ++r) {
                SS += ssum[r * 16 + tid];
                CC += scnt[r * 16 + tid];
            }
            // scalar tail (elements n4*4 .. n-1) — unused for this shape
            const float* x = (const float*)x4;
            for (long long j = n4 * 4; j < n; ++j) {
                if ((int)(j % 16) == tid) {
                    float v = x[j];
                    if (v == v) { SS += v; CC += 1.f; }
                }
            }
            smean[tid] = SS / fmaxf(CC, 1.f);
        }
        __syncthreads();
    }

    // ---- phase B: fill (normal stores) ----
    const int cb = (int)(gid & 3) * 4;  // constant per thread (stride % 4 == 0)
    const float m0 = smean[cb + 0];
    const float m1 = smean[cb + 1];
    const float m2 = smean[cb + 2];
    const float m3 = smean[cb + 3];

#define FIX_ST(v, idx)                                                      \
    do {                                                                    \
        float4 nv;                                                          \
        nv.x = ((v).x == (v).x) ? (v).x : m0;                               \
        nv.y = ((v).y == (v).y) ? (v).y : m1;                               \
        nv.z = ((v).z == (v).z) ? (v).z : m2;                               \
        nv.w = ((v).w == (v).w) ? (v).w : m3;                               \
        o4[idx] = nv;                                                       \
    } while (0)

    // store the prefetched tiles
    if (ha) FIX_ST(pa, gid + 0 * stride);
    if (hb) FIX_ST(pb, gid + 1 * stride);
    if (hc) FIX_ST(pc, gid + 2 * stride);
    if (hd) FIX_ST(pd, gid + 3 * stride);

    long long i = gid + 4 * stride;
    for (; i + 3 * stride < n4; i += 4 * stride) {
        float4 va = x4[i];
        float4 vb = x4[i + stride];
        float4 vc = x4[i + 2 * stride];
        float4 vd = x4[i + 3 * stride];
        FIX_ST(va, i);
        FIX_ST(vb, i + stride);
        FIX_ST(vc, i + 2 * stride);
        FIX_ST(vd, i + 3 * stride);
    }
    for (; i < n4; i += stride) {
        float4 v = x4[i];
        FIX_ST(v, i);
    }
#undef FIX_ST

    if (gid == 0) {  // scalar tail (unused for this shape)
        const float* x = (const float*)x4;
        float* o = (float*)o4;
        for (long long j = n4 * 4; j < n; ++j) {
            float v = x[j];
            o[j] = (v == v) ? v : smean[(int)(j % 16)];
        }
    }
}

extern "C" void kernel_launch(void* const* d_in, const int* in_sizes, int n_in,
                              void* d_out, int out_size, void* d_ws, size_t ws_size,
                              hipStream_t stream) {
    const float* x = (const float*)d_in[0];
    float* out = (float*)d_out;
    const long long n = (long long)in_sizes[0];
    const long long n4 = n / 4;

    // ws layout: [nb1 * 32] partial sums/counts.
    int nb1 = NB1;
    {
        long long cap = (long long)(ws_size / 4) / 32;
        if (cap < 1) cap = 1;
        if (nb1 > cap) nb1 = (int)cap;
    }
    float* partials = (float*)d_ws;

    k_reduce<<<nb1, NT, 0, stream>>>((const float4*)x, n4, partials);
    k_fill<<<NB2, NT, 0, stream>>>((const float4*)x, (float4*)out, n4, n,
                                   partials, nb1);
}